// Round 1
// baseline (293.037 us; speedup 1.0000x reference)
//
#include <hip/hip_runtime.h>

// NADE forward, B=512, D=1024, H=512, C=4.
// Strategy: break the serial scan over D via checkpointing (K chunks),
// then run K*B independent waves, each wave = (batch, d-chunk),
// lanes cover H (8 h per lane, h = lane + 64*j for coalesced loads).
// Pre-transpose V,W,x so all main-loop global loads are coalesced.
// No LDS / no barriers in the main kernel.

#define Bv 512
#define Dv 1024
#define Hv 512
#define Cv 4
#define Kv 16
#define DCv 64   // Dv / Kv

#define L2E 1.4426950408889634f
#define LN2 0.6931471805599453f

__device__ __forceinline__ float fexp2(float x) { return __builtin_amdgcn_exp2f(x); }
__device__ __forceinline__ float flog2(float x) { return __builtin_amdgcn_logf(x); }
__device__ __forceinline__ float frcp(float x)  { return __builtin_amdgcn_rcpf(x); }

// ---- K0a: Vt[d][h][c] = V[h][d][c] (coalesced float4 writes) ----
__global__ void k_transpose_V(const float* __restrict__ V, float* __restrict__ Vt) {
    int gid = blockIdx.x * blockDim.x + threadIdx.x;   // 524288 = H*D
    int h = gid & (Hv - 1);
    int d = gid >> 9;
    const float4 v = *(const float4*)(V + ((size_t)h * Dv + d) * Cv);
    *(float4*)(Vt + ((size_t)d * Hv + h) * Cv) = v;
}

// ---- K0b: Wt[d][h] = W[h][d];  xt[d][b] = x[b][d] ----
__global__ void k_transpose_WX(const float* __restrict__ W, const float* __restrict__ x,
                               float* __restrict__ Wt, float* __restrict__ xt) {
    int gid = blockIdx.x * blockDim.x + threadIdx.x;   // 524288
    int h = gid & (Hv - 1);
    int d = gid >> 9;
    Wt[(size_t)d * Hv + h] = W[(size_t)h * Dv + d];
    xt[(size_t)d * Bv + h] = x[(size_t)h * Dv + d];    // Bv == Hv == 512
}

// ---- K1: P[k][b][h] = sum_{d in chunk k} x[b,d] * W[h,d] ----
// block = (k, bgroup of 8 batches), 512 threads (h)
__global__ void k_partial(const float* __restrict__ xt, const float* __restrict__ Wt,
                          float* __restrict__ P) {
    int k  = blockIdx.x >> 6;
    int bg = blockIdx.x & 63;
    int h  = threadIdx.x;
    int d0 = k * DCv;

    __shared__ float xs[DCv * 8];
    {
        int j = threadIdx.x >> 3;
        int g = threadIdx.x & 7;
        xs[threadIdx.x] = xt[(size_t)(d0 + j) * Bv + bg * 8 + g];
    }
    __syncthreads();

    float acc[8];
#pragma unroll
    for (int g = 0; g < 8; ++g) acc[g] = 0.0f;

    for (int j = 0; j < DCv; ++j) {
        float w = Wt[(size_t)(d0 + j) * Hv + h];
#pragma unroll
        for (int g = 0; g < 8; ++g) acc[g] = fmaf(xs[j * 8 + g], w, acc[g]);
    }
#pragma unroll
    for (int g = 0; g < 8; ++g)
        P[((size_t)k * Bv + bg * 8 + g) * Hv + h] = acc[g];
}

// ---- K2: A0[k][b][h] = c[h] + sum_{k'<k} P[k'][b][h]  (exclusive prefix) ----
__global__ void k_prefix(const float* __restrict__ P, const float* __restrict__ cbias,
                         float* __restrict__ A0) {
    int gid = blockIdx.x * blockDim.x + threadIdx.x;   // 262144 = B*H
    int h = gid & (Hv - 1);
    int b = gid >> 9;
    float run = cbias[h];
    for (int k = 0; k < Kv; ++k) {
        A0[((size_t)k * Bv + b) * Hv + h] = run;
        run += P[((size_t)k * Bv + b) * Hv + h];
    }
}

// ---- K3: main scan. grid = Kv * (Bv/4) blocks, 256 threads = 4 waves.
// wave = one (k, b); lane owns h = lane + 64*j, j=0..7 ----
__global__ __launch_bounds__(256) void k_main(
        const float* __restrict__ x, const float* __restrict__ bbias,
        const float* __restrict__ Vt, const float* __restrict__ Wt,
        const float* __restrict__ A0, float* __restrict__ out) {
    int k    = blockIdx.x >> 7;          // 16 chunks
    int bq   = blockIdx.x & 127;         // 128 groups of 4 batches
    int w    = threadIdx.x >> 6;
    int lane = threadIdx.x & 63;
    int b    = bq * 4 + w;

    float a[8];
#pragma unroll
    for (int j = 0; j < 8; ++j)
        a[j] = A0[((size_t)k * Bv + b) * Hv + lane + 64 * j];

    const int d0 = k * DCv;
    float* yout = out + (size_t)b * Dv * Cv;
    float* pout = out + (size_t)Bv * Dv * Cv + (size_t)b * Dv * Cv;

    for (int d = d0; d < d0 + DCv; ++d) {
        // sigmoid of running preactivation
        float sg[8];
#pragma unroll
        for (int j = 0; j < 8; ++j)
            sg[j] = frcp(1.0f + fexp2(a[j] * (-L2E)));

        float acc0 = 0.f, acc1 = 0.f, acc2 = 0.f, acc3 = 0.f;
#pragma unroll
        for (int j = 0; j < 8; ++j) {
            const float4 v = *(const float4*)(Vt + ((size_t)d * Hv + lane + 64 * j) * Cv);
            acc0 = fmaf(sg[j], v.x, acc0);
            acc1 = fmaf(sg[j], v.y, acc1);
            acc2 = fmaf(sg[j], v.z, acc2);
            acc3 = fmaf(sg[j], v.w, acc3);
        }
        // butterfly reduce over 64 lanes (all lanes end with the sums)
#pragma unroll
        for (int m = 1; m < 64; m <<= 1) {
            acc0 += __shfl_xor(acc0, m);
            acc1 += __shfl_xor(acc1, m);
            acc2 += __shfl_xor(acc2, m);
            acc3 += __shfl_xor(acc3, m);
        }
        const float4 bb = *(const float4*)(bbias + d * Cv);
        float l0 = acc0 + bb.x, l1 = acc1 + bb.y, l2 = acc2 + bb.z, l3 = acc3 + bb.w;

        // log_softmax over C=4
        float mx = fmaxf(fmaxf(l0, l1), fmaxf(l2, l3));
        float s = fexp2((l0 - mx) * L2E) + fexp2((l1 - mx) * L2E) +
                  fexp2((l2 - mx) * L2E) + fexp2((l3 - mx) * L2E);
        float lse = mx + flog2(s) * LN2;

        if (lane < 8) {
            int c = lane & 3;
            float l = (c == 0) ? l0 : (c == 1) ? l1 : (c == 2) ? l2 : l3;
            float val = (lane < 4) ? l : (l - lse);
            float* base = (lane < 4) ? yout : pout;
            base[d * Cv + c] = val;
        }

        // a += x[b,d] * W[:,d]
        float xd = x[(size_t)b * Dv + d];
#pragma unroll
        for (int j = 0; j < 8; ++j)
            a[j] = fmaf(xd, Wt[(size_t)d * Hv + lane + 64 * j], a[j]);
    }
}

extern "C" void kernel_launch(void* const* d_in, const int* in_sizes, int n_in,
                              void* d_out, int out_size, void* d_ws, size_t ws_size,
                              hipStream_t stream) {
    const float* x  = (const float*)d_in[0];   // [B, D]
    const float* V  = (const float*)d_in[1];   // [H, D, C]
    const float* bb = (const float*)d_in[2];   // [D, C]
    const float* W  = (const float*)d_in[3];   // [H, D]
    const float* cb = (const float*)d_in[4];   // [1, H]
    float* out = (float*)d_out;                // [B*D*C] y_hat, then [B*D*C] p_hat

    float* ws = (float*)d_ws;
    float* Vt = ws;                                   // 2097152
    float* Wt = Vt + (size_t)Dv * Hv * Cv;            // 524288
    float* xt = Wt + (size_t)Dv * Hv;                 // 524288
    float* P  = xt + (size_t)Dv * Bv;                 // Kv*Bv*Hv = 4194304
    float* A0 = P + (size_t)Kv * Bv * Hv;             // 4194304
    // total ~46.1 MB of d_ws

    k_transpose_V<<<(Hv * Dv) / 256, 256, 0, stream>>>(V, Vt);
    k_transpose_WX<<<(Hv * Dv) / 256, 256, 0, stream>>>(W, x, Wt, xt);
    k_partial<<<Kv * (Bv / 8), 512, 0, stream>>>(xt, Wt, P);
    k_prefix<<<(Bv * Hv) / 256, 256, 0, stream>>>(P, cb, A0);
    k_main<<<Kv * (Bv / 4), 256, 0, stream>>>(x, bb, Vt, Wt, A0, out);
}

// Round 2
// 262.100 us; speedup vs baseline: 1.1180x; 1.1180x over previous
//
#include <hip/hip_runtime.h>

// NADE forward, B=512, D=1024, H=512, C=4.
// Checkpointed scan over D (K=16 chunks). Main kernel: wave = (chunk, batch),
// lanes cover H (8 h/lane). All preactivations kept in the *log2e-scaled*
// domain so sigmoid = rcp(1+exp2(-a)). Cross-lane reduction uses a
// distributed 4-class scheme: 9 ds_swizzle + 1 ds_bpermute per step.

#define Bv 512
#define Dv 1024
#define Hv 512
#define Cv 4
#define Kv 16
#define DCv 64   // Dv / Kv

#define L2E 1.4426950408889634f
#define LN2 0.6931471805599453f

__device__ __forceinline__ float fexp2(float x) { return __builtin_amdgcn_exp2f(x); }
__device__ __forceinline__ float flog2(float x) { return __builtin_amdgcn_logf(x); }
__device__ __forceinline__ float frcp(float x)  { return __builtin_amdgcn_rcpf(x); }

template<int PAT>
__device__ __forceinline__ float swz(float v) {
    return __int_as_float(__builtin_amdgcn_ds_swizzle(__float_as_int(v), PAT));
}
__device__ __forceinline__ float bperm(int addr, float v) {
    return __int_as_float(__builtin_amdgcn_ds_bpermute(addr, __float_as_int(v)));
}
// ds_swizzle BitMode xor patterns (within 32-lane halves)
#define SWZ_X1  0x041F
#define SWZ_X2  0x081F
#define SWZ_X4  0x101F
#define SWZ_X8  0x201F
#define SWZ_X16 0x401F

// ---- prep: Vt[d][h][c] = V[h][d][c];  WtL[d][h] = W[h][d]*log2e ----
__global__ void k_prep(const float* __restrict__ V, const float* __restrict__ W,
                       float* __restrict__ Vt, float* __restrict__ WtL) {
    int gid = blockIdx.x * blockDim.x + threadIdx.x;   // H*D
    int h = gid & (Hv - 1);
    int d = gid >> 9;
    *(float4*)(Vt + ((size_t)d * Hv + h) * Cv) = *(const float4*)(V + ((size_t)h * Dv + d) * Cv);
    WtL[(size_t)d * Hv + h] = W[(size_t)h * Dv + d] * L2E;
}

// ---- partial sums: P[k][b][h] = sum_{d in chunk k} x[b,d] * WtL[d][h] ----
__global__ __launch_bounds__(512) void k_partial(const float* __restrict__ x,
                          const float* __restrict__ WtL, float* __restrict__ P) {
    int k  = blockIdx.x >> 6;
    int bg = blockIdx.x & 63;
    int h  = threadIdx.x;
    int d0 = k * DCv;

    __shared__ float xs[DCv * 8];
    {
        int g = threadIdx.x >> 6;   // batch within group of 8
        int j = threadIdx.x & 63;   // d within chunk
        xs[j * 8 + g] = x[(size_t)(bg * 8 + g) * Dv + d0 + j];
    }
    __syncthreads();

    float acc[8];
#pragma unroll
    for (int g = 0; g < 8; ++g) acc[g] = 0.0f;

    const float* wp = WtL + (size_t)d0 * Hv + h;
    for (int j = 0; j < DCv; ++j) {
        float wv = wp[(size_t)j * Hv];
        const float4 x0 = *(const float4*)(xs + j * 8);
        const float4 x1 = *(const float4*)(xs + j * 8 + 4);
        acc[0] = fmaf(x0.x, wv, acc[0]);
        acc[1] = fmaf(x0.y, wv, acc[1]);
        acc[2] = fmaf(x0.z, wv, acc[2]);
        acc[3] = fmaf(x0.w, wv, acc[3]);
        acc[4] = fmaf(x1.x, wv, acc[4]);
        acc[5] = fmaf(x1.y, wv, acc[5]);
        acc[6] = fmaf(x1.z, wv, acc[6]);
        acc[7] = fmaf(x1.w, wv, acc[7]);
    }
#pragma unroll
    for (int g = 0; g < 8; ++g)
        P[((size_t)k * Bv + bg * 8 + g) * Hv + h] = acc[g];
}

// ---- exclusive prefix over chunks: A0[k][b][h] (scaled domain) ----
__global__ void k_prefix(const float* __restrict__ P, const float* __restrict__ cbias,
                         float* __restrict__ A0) {
    int gid = blockIdx.x * blockDim.x + threadIdx.x;   // B*H
    int h = gid & (Hv - 1);
    int b = gid >> 9;
    float run = cbias[h] * L2E;
    for (int k = 0; k < Kv; ++k) {
        A0[((size_t)k * Bv + b) * Hv + h] = run;
        run += P[((size_t)k * Bv + b) * Hv + h];
    }
}

// ---- main scan: grid = Kv*(Bv/4) blocks of 256; wave = (k, b) ----
__global__ __launch_bounds__(256) void k_main(
        const float* __restrict__ x, const float* __restrict__ bbias,
        const float* __restrict__ Vt, const float* __restrict__ WtL,
        const float* __restrict__ A0, float* __restrict__ out) {
    const int k    = blockIdx.x >> 7;
    const int bq   = blockIdx.x & 127;
    const int wid  = threadIdx.x >> 6;
    const int lane = threadIdx.x & 63;
    const int b    = bq * 4 + wid;
    const int d0   = k * DCv;
    const int cm   = ((lane & 1) << 1) | ((lane >> 1) & 1);  // class owned by this lane
    const int addr32 = (lane ^ 32) << 2;                      // bpermute byte addr

    float a[8];
#pragma unroll
    for (int j = 0; j < 8; ++j)
        a[j] = A0[((size_t)k * Bv + b) * Hv + lane + 64 * j];

    // chunk's x values, one per lane; broadcast via readlane in-loop
    const float xr = x[(size_t)b * Dv + d0 + lane];

    const float* vp = Vt + ((size_t)d0 * Hv + lane) * Cv;
    const float* wp = WtL + (size_t)d0 * Hv + lane;
    const float* bp = bbias + d0 * Cv;
    float* sp = out + ((lane & 4) ? (size_t)Bv * Dv * Cv : (size_t)0)
                    + (size_t)b * Dv * Cv + (size_t)d0 * Cv + cm;
    const bool storer = (lane < 8);
    const bool is_y   = (lane < 4);

#pragma unroll 2
    for (int i = 0; i < DCv; ++i) {
        // sigmoid (scaled domain): 3 ops per h
        float sg[8];
#pragma unroll
        for (int j = 0; j < 8; ++j)
            sg[j] = frcp(1.0f + fexp2(-a[j]));

        float acc0 = 0.f, acc1 = 0.f, acc2 = 0.f, acc3 = 0.f;
#pragma unroll
        for (int j = 0; j < 8; ++j) {
            const float4 v = *(const float4*)(vp + j * (64 * Cv));
            acc0 = fmaf(sg[j], v.x, acc0);
            acc1 = fmaf(sg[j], v.y, acc1);
            acc2 = fmaf(sg[j], v.z, acc2);
            acc3 = fmaf(sg[j], v.w, acc3);
        }

        // next-step preactivation early (independent of reduce below -> ILP)
        {
            float xd = __int_as_float(__builtin_amdgcn_readlane(__float_as_int(xr), i));
#pragma unroll
            for (int j = 0; j < 8; ++j)
                a[j] = fmaf(xd, wp[j * 64], a[j]);
        }

        // distributed 4-class reduce over 64 lanes: 10 cross-lane ops
        float t0 = acc0 + swz<SWZ_X1>(acc0);
        float t1 = acc1 + swz<SWZ_X1>(acc1);
        float t2 = acc2 + swz<SWZ_X1>(acc2);
        float t3 = acc3 + swz<SWZ_X1>(acc3);
        float u  = (lane & 1) ? t2 : t0;
        float vv = (lane & 1) ? t3 : t1;
        u  += swz<SWZ_X2>(u);
        vv += swz<SWZ_X2>(vv);
        float w = (lane & 2) ? vv : u;   // lane now owns class cm
        w += swz<SWZ_X4>(w);
        w += swz<SWZ_X8>(w);
        w += swz<SWZ_X16>(w);
        w += bperm(addr32, w);           // cross-32 half
        w += bp[cm];                     // logit for class cm (all lanes)

        // log-softmax across the quad's 4 classes
        float m = fmaxf(w, swz<SWZ_X1>(w));
        m = fmaxf(m, swz<SWZ_X2>(m));
        float e = fexp2((w - m) * L2E);
        float s = e + swz<SWZ_X1>(e);
        s += swz<SWZ_X2>(s);
        float lse = m + flog2(s) * LN2;
        float p = w - lse;

        if (storer) sp[0] = is_y ? w : p;

        sp += Cv; vp += Hv * Cv; wp += Hv; bp += Cv;
    }
}

extern "C" void kernel_launch(void* const* d_in, const int* in_sizes, int n_in,
                              void* d_out, int out_size, void* d_ws, size_t ws_size,
                              hipStream_t stream) {
    const float* x  = (const float*)d_in[0];   // [B, D]
    const float* V  = (const float*)d_in[1];   // [H, D, C]
    const float* bb = (const float*)d_in[2];   // [D, C]
    const float* W  = (const float*)d_in[3];   // [H, D]
    const float* cb = (const float*)d_in[4];   // [1, H]
    float* out = (float*)d_out;                // y_hat [B*D*C] then p_hat [B*D*C]

    float* ws  = (float*)d_ws;
    float* Vt  = ws;                               // D*H*C   = 2097152
    float* WtL = Vt + (size_t)Dv * Hv * Cv;        // D*H     = 524288
    float* P   = WtL + (size_t)Dv * Hv;            // K*B*H   = 4194304
    float* A0  = P + (size_t)Kv * Bv * Hv;         // K*B*H   = 4194304

    k_prep<<<(Hv * Dv) / 256, 256, 0, stream>>>(V, W, Vt, WtL);
    k_partial<<<Kv * (Bv / 8), 512, 0, stream>>>(x, WtL, P);
    k_prefix<<<(Bv * Hv) / 256, 256, 0, stream>>>(P, cb, A0);
    k_main<<<Kv * (Bv / 4), 256, 0, stream>>>(x, bb, Vt, WtL, A0, out);
}

// Round 3
// 184.419 us; speedup vs baseline: 1.5890x; 1.4212x over previous
//
#include <hip/hip_runtime.h>

// NADE forward, B=512, D=1024, H=512, C=4.
// Checkpointed scan over D (K=32 chunks). Main kernel: workgroup = 16 batches,
// 4 waves = 4 H-slices of 128. Logit GEMV per d-step via bf16 MFMA 16x16x32:
//   A = V (M rows = classes, rows 4..15 zero), B = sigma(a) (N cols = batches).
// C/D layout puts each batch's 4 classes in one lane's 4 regs -> in-lane softmax.
// Cross-wave H-reduce: 1 ds_write_b128 + 4 ds_read_b128 + 1 barrier per step.
// Preactivations kept in log2e-scaled domain: sigma = rcp(1+exp2(-a)).

#define Bv 512
#define Dv 1024
#define Hv 512
#define Cv 4
#define Kv 32
#define DCv 32   // Dv / Kv

#define L2E 1.4426950408889634f
#define LN2 0.6931471805599453f

typedef __attribute__((ext_vector_type(8))) short short8;
typedef __attribute__((ext_vector_type(4))) float f32x4;

__device__ __forceinline__ float fexp2(float x) { return __builtin_amdgcn_exp2f(x); }
__device__ __forceinline__ float flog2(float x) { return __builtin_amdgcn_logf(x); }
__device__ __forceinline__ float frcp(float x)  { return __builtin_amdgcn_rcpf(x); }

// pack two f32 -> bf16x2 by truncation (1 v_perm_b32)
__device__ __forceinline__ unsigned bf16pk(float lo, float hi) {
    return __builtin_amdgcn_perm(__float_as_uint(hi), __float_as_uint(lo), 0x07060302u);
}
__device__ __forceinline__ unsigned short bf16rne(float f) {
    unsigned u = __float_as_uint(f);
    return (unsigned short)((u + 0x7FFFu + ((u >> 16) & 1u)) >> 16);
}

// ---- prep: WtL[d][h] = W[h][d]*log2e ; xt[d][b] = x[b][d] ----
__global__ void k_prep(const float* __restrict__ W, const float* __restrict__ x,
                       float* __restrict__ WtL, float* __restrict__ xt) {
    int gid = blockIdx.x * blockDim.x + threadIdx.x;   // H*D
    int h = gid & (Hv - 1);
    int d = gid >> 9;
    WtL[(size_t)d * Hv + h] = W[(size_t)h * Dv + d] * L2E;
    xt[(size_t)d * Bv + h]  = x[(size_t)h * Dv + d];   // Bv == Hv
}

// ---- prep V -> VtA4: MFMA A-operand fragments, bf16 RNE, classes only ----
// VtA4[(d*16 + hb)*16 + (quad*4 + c)][j]  (8 bf16 = 16B per entry)
// element = V[h = hb*32 + quad*8 + j][d][c]
__global__ __launch_bounds__(256) void k_prepv(const float* __restrict__ V,
                                               unsigned short* __restrict__ VtA4) {
    __shared__ unsigned short tile[16 * 16 * 16 * 8];  // 64 KiB
    int d0   = blockIdx.x * 16;
    int hloc = threadIdx.x >> 4;
    int dd   = threadIdx.x & 15;
    for (int pass = 0; pass < 32; ++pass) {
        int h = pass * 16 + hloc;
        float4 v = *(const float4*)(V + ((size_t)h * Dv + d0 + dd) * Cv);
        int hb = h >> 5, q = (h >> 3) & 3, j = h & 7;
        int base = ((dd * 16 + hb) * 16 + q * 4) * 8 + j;
        tile[base + 0 * 8] = bf16rne(v.x);
        tile[base + 1 * 8] = bf16rne(v.y);
        tile[base + 2 * 8] = bf16rne(v.z);
        tile[base + 3 * 8] = bf16rne(v.w);
    }
    __syncthreads();
    uint4* dst = (uint4*)(VtA4 + (size_t)d0 * 16 * 16 * 8);
    const uint4* src = (const uint4*)tile;
    for (int t = threadIdx.x; t < 4096; t += 256) dst[t] = src[t];
}

// ---- partials into A0: A0[k][b][h] = sum_{d in chunk k} x[b,d]*WtL[d][h] ----
__global__ __launch_bounds__(512) void k_partial(const float* __restrict__ x,
                          const float* __restrict__ WtL, float* __restrict__ A0) {
    int k  = blockIdx.x >> 6;
    int bg = blockIdx.x & 63;
    int h  = threadIdx.x;
    int d0 = k * DCv;

    __shared__ float xs[DCv * 8];
    if (threadIdx.x < DCv * 8) {
        int g = threadIdx.x >> 5;   // batch in group of 8
        int j = threadIdx.x & 31;   // d in chunk
        xs[j * 8 + g] = x[(size_t)(bg * 8 + g) * Dv + d0 + j];
    }
    __syncthreads();

    float acc[8];
#pragma unroll
    for (int g = 0; g < 8; ++g) acc[g] = 0.0f;

    const float* wp = WtL + (size_t)d0 * Hv + h;
    for (int j = 0; j < DCv; ++j) {
        float wv = wp[(size_t)j * Hv];
        const float4 x0 = *(const float4*)(xs + j * 8);
        const float4 x1 = *(const float4*)(xs + j * 8 + 4);
        acc[0] = fmaf(x0.x, wv, acc[0]);
        acc[1] = fmaf(x0.y, wv, acc[1]);
        acc[2] = fmaf(x0.z, wv, acc[2]);
        acc[3] = fmaf(x0.w, wv, acc[3]);
        acc[4] = fmaf(x1.x, wv, acc[4]);
        acc[5] = fmaf(x1.y, wv, acc[5]);
        acc[6] = fmaf(x1.z, wv, acc[6]);
        acc[7] = fmaf(x1.w, wv, acc[7]);
    }
#pragma unroll
    for (int g = 0; g < 8; ++g)
        A0[((size_t)k * Bv + bg * 8 + g) * Hv + h] = acc[g];
}

// ---- in-place exclusive prefix over chunks, seeded with c*log2e ----
__global__ void k_prefix(float* __restrict__ A0, const float* __restrict__ cbias) {
    int gid = blockIdx.x * blockDim.x + threadIdx.x;   // B*H
    int h = gid & (Hv - 1);
    int bi = gid >> 9;
    float run = cbias[h] * L2E;
    float* p = A0 + (size_t)bi * Hv + h;
    for (int k = 0; k < Kv; ++k) {
        float t = p[(size_t)k * Bv * Hv];
        p[(size_t)k * Bv * Hv] = run;
        run += t;
    }
}

// ---- main scan: grid = Kv*32 blocks of 256 (4 waves = 4 H-slices) ----
__global__ __launch_bounds__(256, 4) void k_main(
        const float* __restrict__ xt, const float* __restrict__ bbias,
        const unsigned short* __restrict__ VtA4, const float* __restrict__ WtL,
        const float* __restrict__ A0, float* __restrict__ out) {
    const int k    = blockIdx.x >> 5;
    const int bg   = blockIdx.x & 31;
    const int wid  = threadIdx.x >> 6;   // H-slice
    const int lane = threadIdx.x & 63;
    const int bl   = lane & 15;          // batch col (B-op) / class row m (A-op)
    const int quad = lane >> 4;          // k-group within K=32
    const int b    = bg * 16 + bl;
    const int d0   = k * DCv;

    __shared__ f32x4 red[2][4][64];      // 8 KiB double-buffered partials

    // a state: h = wid*128 + kb*32 + quad*8 + j (scaled domain)
    float a[32];
    {
        const float* ap = A0 + ((size_t)k * Bv + b) * Hv + wid * 128 + quad * 8;
#pragma unroll
        for (int kb = 0; kb < 4; ++kb) {
            float4 t0 = *(const float4*)(ap + kb * 32);
            float4 t1 = *(const float4*)(ap + kb * 32 + 4);
            a[kb*8+0]=t0.x; a[kb*8+1]=t0.y; a[kb*8+2]=t0.z; a[kb*8+3]=t0.w;
            a[kb*8+4]=t1.x; a[kb*8+5]=t1.y; a[kb*8+6]=t1.z; a[kb*8+7]=t1.w;
        }
    }

    const bool act = (bl < 4);           // lanes carrying real V rows (classes)
    const unsigned short* vp = VtA4 + (((size_t)d0 * 16 + wid * 4) * 16 + quad * 4 + bl) * 8;
    const float* wp = WtL + (size_t)d0 * Hv + wid * 128 + quad * 8;
    const float* xp = xt + (size_t)d0 * Bv + b;
    const float* bp = bbias + d0 * Cv;
    float* yp = out + (size_t)b * Dv * Cv + d0 * Cv;
    float* pp = yp + (size_t)Bv * Dv * Cv;

    const short8 zfrag = {0,0,0,0,0,0,0,0};

    for (int i = 0; i < DCv; ++i) {
        // prefetch V fragments, x, bias
        short8 af[4];
#pragma unroll
        for (int kb = 0; kb < 4; ++kb)
            af[kb] = act ? *(const short8*)(vp + kb * 128) : zfrag;
        float xd = xp[0];
        float4 bbv = *(const float4*)bp;

        // sigmoid (scaled domain) + bf16 pack
        unsigned pk[16];
#pragma unroll
        for (int m = 0; m < 32; m += 2) {
            float s0 = frcp(1.0f + fexp2(-a[m]));
            float s1 = frcp(1.0f + fexp2(-a[m + 1]));
            pk[m >> 1] = bf16pk(s0, s1);
        }

        // advance preactivation to next d (independent of MFMA)
#pragma unroll
        for (int kb = 0; kb < 4; ++kb)
#pragma unroll
            for (int j = 0; j < 8; ++j)
                a[kb*8+j] = fmaf(xd, wp[kb*32+j], a[kb*8+j]);

        // partial logits for this H-slice: D[class][batch]
        f32x4 acc = {0.f, 0.f, 0.f, 0.f};
#pragma unroll
        for (int kb = 0; kb < 4; ++kb) {
            union { unsigned u[4]; short8 s; } cv;
            cv.u[0] = pk[kb*4+0]; cv.u[1] = pk[kb*4+1];
            cv.u[2] = pk[kb*4+2]; cv.u[3] = pk[kb*4+3];
            acc = __builtin_amdgcn_mfma_f32_16x16x32_bf16(af[kb], cv.s, acc, 0, 0, 0);
        }

        red[i & 1][wid][lane] = acc;
        __syncthreads();
        f32x4 r0 = red[i & 1][0][lane];
        f32x4 r1 = red[i & 1][1][lane];
        f32x4 r2 = red[i & 1][2][lane];
        f32x4 r3 = red[i & 1][3][lane];
        float w0 = r0.x + r1.x + r2.x + r3.x + bbv.x;
        float w1 = r0.y + r1.y + r2.y + r3.y + bbv.y;
        float w2 = r0.z + r1.z + r2.z + r3.z + bbv.z;
        float w3 = r0.w + r1.w + r2.w + r3.w + bbv.w;

        // in-lane log-softmax over the 4 classes (valid on quad==0 lanes)
        float mx = fmaxf(fmaxf(w0, w1), fmaxf(w2, w3));
        float e0 = fexp2((w0 - mx) * L2E);
        float e1 = fexp2((w1 - mx) * L2E);
        float e2 = fexp2((w2 - mx) * L2E);
        float e3 = fexp2((w3 - mx) * L2E);
        float lse = mx + flog2(e0 + e1 + e2 + e3) * LN2;

        if (quad == 0) {
            if (wid == 0) {
                *(float4*)yp = make_float4(w0, w1, w2, w3);
            } else if (wid == 1) {
                *(float4*)pp = make_float4(w0 - lse, w1 - lse, w2 - lse, w3 - lse);
            }
        }

        vp += 16 * 16 * 8;   // next d
        wp += Hv;
        xp += Bv;
        bp += Cv;
        yp += Cv;
        pp += Cv;
    }
}

extern "C" void kernel_launch(void* const* d_in, const int* in_sizes, int n_in,
                              void* d_out, int out_size, void* d_ws, size_t ws_size,
                              hipStream_t stream) {
    const float* x  = (const float*)d_in[0];   // [B, D]
    const float* V  = (const float*)d_in[1];   // [H, D, C]
    const float* bb = (const float*)d_in[2];   // [D, C]
    const float* W  = (const float*)d_in[3];   // [H, D]
    const float* cb = (const float*)d_in[4];   // [1, H]
    float* out = (float*)d_out;                // y_hat [B*D*C] then p_hat

    char* ws = (char*)d_ws;
    unsigned short* VtA4 = (unsigned short*)ws;                 // 4 MiB
    float* WtL = (float*)(ws + (size_t)4 * 1024 * 1024);        // 2 MiB
    float* xt  = (float*)(ws + (size_t)6 * 1024 * 1024);        // 2 MiB
    float* A0  = (float*)(ws + (size_t)8 * 1024 * 1024);        // 32 MiB (K*B*H)

    k_prep<<<(Hv * Dv) / 256, 256, 0, stream>>>(W, x, WtL, xt);
    k_prepv<<<Dv / 16, 256, 0, stream>>>(V, VtA4);
    k_partial<<<Kv * (Bv / 8), 512, 0, stream>>>(x, WtL, A0);
    k_prefix<<<(Bv * Hv) / 256, 256, 0, stream>>>(A0, cb);
    k_main<<<Kv * 32, 256, 0, stream>>>(xt, bb, VtA4, WtL, A0, out);
}

// Round 4
// 169.472 us; speedup vs baseline: 1.7291x; 1.0882x over previous
//
#include <hip/hip_runtime.h>

// NADE forward, B=512, D=1024, H=512, C=4.
// Checkpointed scan over D (K=32 chunks). Main kernel: workgroup = 16 batches,
// 4 waves = 4 H-slices of 128. Logit GEMV per d-step via bf16 MFMA 16x16x32:
//   A = V (M rows = classes, rows 4..15 zero), B = sigma(a) (N cols = batches).
// d-steps processed in PAIRS: one barrier per 2 steps; epilogue role-split
// across waves (wid0: y stepA, wid1: p stepA, wid2: y stepB, wid3: p stepB).
// Preactivations kept in log2e-scaled domain: sigma = rcp(1+exp2(-a)).

#define Bv 512
#define Dv 1024
#define Hv 512
#define Cv 4
#define Kv 32
#define DCv 32   // Dv / Kv

#define L2E 1.4426950408889634f
#define LN2 0.6931471805599453f

typedef __attribute__((ext_vector_type(8))) short short8;
typedef __attribute__((ext_vector_type(4))) float f32x4;

__device__ __forceinline__ float fexp2(float x) { return __builtin_amdgcn_exp2f(x); }
__device__ __forceinline__ float flog2(float x) { return __builtin_amdgcn_logf(x); }
__device__ __forceinline__ float frcp(float x)  { return __builtin_amdgcn_rcpf(x); }

// pack two f32 -> bf16x2 by truncation (1 v_perm_b32)
__device__ __forceinline__ unsigned bf16pk(float lo, float hi) {
    return __builtin_amdgcn_perm(__float_as_uint(hi), __float_as_uint(lo), 0x07060302u);
}
__device__ __forceinline__ unsigned short bf16rne(float f) {
    unsigned u = __float_as_uint(f);
    return (unsigned short)((u + 0x7FFFu + ((u >> 16) & 1u)) >> 16);
}

// ---- prep: LDS-tiled transposes. WtL[d][h]=W[h][d]*L2E ; xt[d][b]=x[b][d] ----
// Both sources are [512][1024] f32. 64x64 tiles: 128 tiles per matrix.
__global__ __launch_bounds__(256) void k_prep(const float* __restrict__ W,
                                              const float* __restrict__ x,
                                              float* __restrict__ WtL,
                                              float* __restrict__ xt) {
    __shared__ float t[64][65];
    const int mb   = blockIdx.x >> 7;          // 0: W, 1: x
    const int tile = blockIdx.x & 127;
    const int tr   = tile >> 4;                // src row tile (h/b), 0..7
    const int tc   = tile & 15;                // src col tile (d),   0..15
    const float* src = mb ? x : W;
    float* dst       = mb ? xt : WtL;
    const float scale = mb ? 1.0f : L2E;
    const int lx = threadIdx.x & 15;
    const int ly = threadIdx.x >> 4;

#pragma unroll
    for (int r = 0; r < 64; r += 16) {
        int row = r + ly;
        float4 v = *(const float4*)(src + (size_t)(tr * 64 + row) * Dv + tc * 64 + lx * 4);
        t[row][lx * 4 + 0] = v.x;
        t[row][lx * 4 + 1] = v.y;
        t[row][lx * 4 + 2] = v.z;
        t[row][lx * 4 + 3] = v.w;
    }
    __syncthreads();
#pragma unroll
    for (int r = 0; r < 64; r += 16) {
        int row = r + ly;   // d within tile
        float4 o = make_float4(t[lx * 4 + 0][row] * scale,
                               t[lx * 4 + 1][row] * scale,
                               t[lx * 4 + 2][row] * scale,
                               t[lx * 4 + 3][row] * scale);
        *(float4*)(dst + (size_t)(tc * 64 + row) * 512 + tr * 64 + lx * 4) = o;
    }
}

// ---- prep V -> VtA4 fragments (bf16 RNE). 256 blocks, d-tile of 4. ----
// VtA4[((d*16 + hb)*16 + q*4 + c)*8 + j], element = V[h=hb*32+q*8+j][d][c]
__global__ __launch_bounds__(256) void k_prepv(const float* __restrict__ V,
                                               unsigned short* __restrict__ VtA4) {
    __shared__ unsigned short tile[4 * 16 * 16 * 8];   // 16 KiB
    const int d0 = blockIdx.x * 4;
    const int dd = threadIdx.x & 3;
    const int hb0 = threadIdx.x >> 2;   // 64 h per pass
#pragma unroll
    for (int p = 0; p < 8; ++p) {
        int h = p * 64 + hb0;
        float4 v = *(const float4*)(V + ((size_t)h * Dv + d0 + dd) * Cv);
        int hb = h >> 5, q = (h >> 3) & 3, j = h & 7;
        int base = ((dd * 16 + hb) * 16 + q * 4) * 8 + j;
        tile[base + 0 * 8] = bf16rne(v.x);
        tile[base + 1 * 8] = bf16rne(v.y);
        tile[base + 2 * 8] = bf16rne(v.z);
        tile[base + 3 * 8] = bf16rne(v.w);
    }
    __syncthreads();
    uint4* dst = (uint4*)(VtA4 + (size_t)d0 * 2048);
    const uint4* src = (const uint4*)tile;
    for (int tt = threadIdx.x; tt < 1024; tt += 256) dst[tt] = src[tt];
}

// ---- partials into A0: A0[k][b][h] = sum_{d in chunk k} x[b,d]*WtL[d][h] ----
__global__ __launch_bounds__(512) void k_partial(const float* __restrict__ x,
                          const float* __restrict__ WtL, float* __restrict__ A0) {
    int k  = blockIdx.x >> 6;
    int bg = blockIdx.x & 63;
    int h  = threadIdx.x;
    int d0 = k * DCv;

    __shared__ float xs[DCv * 8];
    if (threadIdx.x < DCv * 8) {
        int g = threadIdx.x >> 5;   // batch in group of 8
        int j = threadIdx.x & 31;   // d in chunk
        xs[j * 8 + g] = x[(size_t)(bg * 8 + g) * Dv + d0 + j];
    }
    __syncthreads();

    float acc[8];
#pragma unroll
    for (int g = 0; g < 8; ++g) acc[g] = 0.0f;

    const float* wp = WtL + (size_t)d0 * Hv + h;
    for (int j = 0; j < DCv; ++j) {
        float wv = wp[(size_t)j * Hv];
        const float4 x0 = *(const float4*)(xs + j * 8);
        const float4 x1 = *(const float4*)(xs + j * 8 + 4);
        acc[0] = fmaf(x0.x, wv, acc[0]);
        acc[1] = fmaf(x0.y, wv, acc[1]);
        acc[2] = fmaf(x0.z, wv, acc[2]);
        acc[3] = fmaf(x0.w, wv, acc[3]);
        acc[4] = fmaf(x1.x, wv, acc[4]);
        acc[5] = fmaf(x1.y, wv, acc[5]);
        acc[6] = fmaf(x1.z, wv, acc[6]);
        acc[7] = fmaf(x1.w, wv, acc[7]);
    }
#pragma unroll
    for (int g = 0; g < 8; ++g)
        A0[((size_t)k * Bv + bg * 8 + g) * Hv + h] = acc[g];
}

// ---- in-place exclusive prefix over chunks, seeded with c*log2e ----
__global__ void k_prefix(float* __restrict__ A0, const float* __restrict__ cbias) {
    int gid = blockIdx.x * blockDim.x + threadIdx.x;   // B*H
    int h = gid & (Hv - 1);
    int bi = gid >> 9;
    float run = cbias[h] * L2E;
    float* p = A0 + (size_t)bi * Hv + h;
    for (int k = 0; k < Kv; ++k) {
        float t = p[(size_t)k * Bv * Hv];
        p[(size_t)k * Bv * Hv] = run;
        run += t;
    }
}

// ---- main scan: grid = Kv*32 blocks of 256 (4 waves = 4 H-slices) ----
__global__ __launch_bounds__(256, 4) void k_main(
        const float* __restrict__ xt, const float* __restrict__ bbias,
        const unsigned short* __restrict__ VtA4, const float* __restrict__ WtL,
        const float* __restrict__ A0, float* __restrict__ out) {
    const int k    = blockIdx.x >> 5;
    const int bg   = blockIdx.x & 31;
    const int wid  = threadIdx.x >> 6;   // H-slice / epilogue role
    const int lane = threadIdx.x & 63;
    const int bl   = lane & 15;          // batch col (B-op) / class row m (A-op)
    const int quad = lane >> 4;
    const int b    = bg * 16 + bl;
    const int d0   = k * DCv;
    const int stp  = wid >> 1;           // which step of the pair this wave stores
    const bool isP = wid & 1;            // y vs p output

    __shared__ f32x4 red[2][2][4][64];   // [pairbuf][step][wid][lane], 16 KiB

    // a state: h = wid*128 + kb*32 + quad*8 + j (scaled domain)
    float a[32];
    {
        const float* ap = A0 + ((size_t)k * Bv + b) * Hv + wid * 128 + quad * 8;
#pragma unroll
        for (int kb = 0; kb < 4; ++kb) {
            float4 t0 = *(const float4*)(ap + kb * 32);
            float4 t1 = *(const float4*)(ap + kb * 32 + 4);
            a[kb*8+0]=t0.x; a[kb*8+1]=t0.y; a[kb*8+2]=t0.z; a[kb*8+3]=t0.w;
            a[kb*8+4]=t1.x; a[kb*8+5]=t1.y; a[kb*8+6]=t1.z; a[kb*8+7]=t1.w;
        }
    }

    const bool act = (bl < 4);
    const unsigned short* vp = VtA4 + (((size_t)d0 * 16 + wid * 4) * 16 + quad * 4 + bl) * 8;
    const float* wp = WtL + (size_t)d0 * Hv + wid * 128 + quad * 8;
    const float* xp = xt + (size_t)d0 * Bv + b;
    const float* bp = bbias + (d0 + stp) * Cv;
    float* sp = out + (isP ? (size_t)Bv * Dv * Cv : (size_t)0)
                    + (size_t)b * Dv * Cv + (d0 + stp) * Cv;

    const short8 zfrag = {0,0,0,0,0,0,0,0};

    for (int i1 = 0; i1 < DCv / 2; ++i1) {
        // fragment / scalar prefetch for both steps of the pair
        short8 afA[4], afB[4];
#pragma unroll
        for (int kb = 0; kb < 4; ++kb)
            afA[kb] = act ? *(const short8*)(vp + kb * 128) : zfrag;
#pragma unroll
        for (int kb = 0; kb < 4; ++kb)
            afB[kb] = act ? *(const short8*)(vp + 2048 + kb * 128) : zfrag;
        float xdA = xp[0];
        float xdB = xp[Bv];
        float4 bbv = *(const float4*)bp;   // this wave's step's bias

        // ---- step A: sigmoid + pack + MFMA ----
        unsigned pkA[16];
#pragma unroll
        for (int m = 0; m < 32; m += 2) {
            float s0 = frcp(1.0f + fexp2(-a[m]));
            float s1 = frcp(1.0f + fexp2(-a[m + 1]));
            pkA[m >> 1] = bf16pk(s0, s1);
        }
        f32x4 accA = {0.f, 0.f, 0.f, 0.f};
#pragma unroll
        for (int kb = 0; kb < 4; ++kb) {
            union { unsigned u[4]; short8 s; } cv;
            cv.u[0] = pkA[kb*4+0]; cv.u[1] = pkA[kb*4+1];
            cv.u[2] = pkA[kb*4+2]; cv.u[3] = pkA[kb*4+3];
            accA = __builtin_amdgcn_mfma_f32_16x16x32_bf16(afA[kb], cv.s, accA, 0, 0, 0);
        }
        // advance a to step B
#pragma unroll
        for (int kb = 0; kb < 4; ++kb)
#pragma unroll
            for (int j = 0; j < 8; ++j)
                a[kb*8+j] = fmaf(xdA, wp[kb*32+j], a[kb*8+j]);

        // ---- step B: sigmoid + pack + MFMA ----
        unsigned pkB[16];
#pragma unroll
        for (int m = 0; m < 32; m += 2) {
            float s0 = frcp(1.0f + fexp2(-a[m]));
            float s1 = frcp(1.0f + fexp2(-a[m + 1]));
            pkB[m >> 1] = bf16pk(s0, s1);
        }
        f32x4 accB = {0.f, 0.f, 0.f, 0.f};
#pragma unroll
        for (int kb = 0; kb < 4; ++kb) {
            union { unsigned u[4]; short8 s; } cv;
            cv.u[0] = pkB[kb*4+0]; cv.u[1] = pkB[kb*4+1];
            cv.u[2] = pkB[kb*4+2]; cv.u[3] = pkB[kb*4+3];
            accB = __builtin_amdgcn_mfma_f32_16x16x32_bf16(afB[kb], cv.s, accB, 0, 0, 0);
        }
        // advance a to next pair
#pragma unroll
        for (int kb = 0; kb < 4; ++kb)
#pragma unroll
            for (int j = 0; j < 8; ++j)
                a[kb*8+j] = fmaf(xdB, wp[Hv + kb*32+j], a[kb*8+j]);

        // ---- cross-wave reduce: one barrier per pair ----
        red[i1 & 1][0][wid][lane] = accA;
        red[i1 & 1][1][wid][lane] = accB;
        __syncthreads();

        f32x4 r0 = red[i1 & 1][stp][0][lane];
        f32x4 r1 = red[i1 & 1][stp][1][lane];
        f32x4 r2 = red[i1 & 1][stp][2][lane];
        f32x4 r3 = red[i1 & 1][stp][3][lane];
        float w0 = r0.x + r1.x + r2.x + r3.x + bbv.x;
        float w1 = r0.y + r1.y + r2.y + r3.y + bbv.y;
        float w2 = r0.z + r1.z + r2.z + r3.z + bbv.z;
        float w3 = r0.w + r1.w + r2.w + r3.w + bbv.w;

        if (!isP) {
            if (quad == 0) *(float4*)sp = make_float4(w0, w1, w2, w3);
        } else {
            float mx = fmaxf(fmaxf(w0, w1), fmaxf(w2, w3));
            float e0 = fexp2((w0 - mx) * L2E);
            float e1 = fexp2((w1 - mx) * L2E);
            float e2 = fexp2((w2 - mx) * L2E);
            float e3 = fexp2((w3 - mx) * L2E);
            float lse = mx + flog2(e0 + e1 + e2 + e3) * LN2;
            if (quad == 0)
                *(float4*)sp = make_float4(w0 - lse, w1 - lse, w2 - lse, w3 - lse);
        }

        vp += 2 * 2048;    // 2 d-steps
        wp += 2 * Hv;
        xp += 2 * Bv;
        bp += 2 * Cv;
        sp += 2 * Cv;
    }
}

extern "C" void kernel_launch(void* const* d_in, const int* in_sizes, int n_in,
                              void* d_out, int out_size, void* d_ws, size_t ws_size,
                              hipStream_t stream) {
    const float* x  = (const float*)d_in[0];   // [B, D]
    const float* V  = (const float*)d_in[1];   // [H, D, C]
    const float* bb = (const float*)d_in[2];   // [D, C]
    const float* W  = (const float*)d_in[3];   // [H, D]
    const float* cb = (const float*)d_in[4];   // [1, H]
    float* out = (float*)d_out;                // y_hat [B*D*C] then p_hat

    char* ws = (char*)d_ws;
    unsigned short* VtA4 = (unsigned short*)ws;                 // 4 MiB
    float* WtL = (float*)(ws + (size_t)4 * 1024 * 1024);        // 2 MiB
    float* xt  = (float*)(ws + (size_t)6 * 1024 * 1024);        // 2 MiB
    float* A0  = (float*)(ws + (size_t)8 * 1024 * 1024);        // 32 MiB (K*B*H)

    k_prep<<<256, 256, 0, stream>>>(W, x, WtL, xt);
    k_prepv<<<Dv / 4, 256, 0, stream>>>(V, VtA4);
    k_partial<<<Kv * (Bv / 8), 512, 0, stream>>>(x, WtL, A0);
    k_prefix<<<(Bv * Hv) / 256, 256, 0, stream>>>(A0, cb);
    k_main<<<Kv * 32, 256, 0, stream>>>(xt, bb, VtA4, WtL, A0, out);
}